// Round 1
// baseline (100.526 us; speedup 1.0000x reference)
//
#include <hip/hip_runtime.h>
#include <hip/hip_bf16.h>

// DistMult score: out[b] = sum_d src[b,d] * M[rel,d] * dst[b,d]
// B=500000, D=128. Pure streaming, memory-bound (~514 MB traffic).
//
// Layout: 32 lanes per row, each lane owns one float4 (4 floats) of the
// 128-wide row. A wave64 covers 2 consecutive rows -> each vector load is a
// contiguous 1 KiB wave-transaction (perfect coalescing). Reduction via
// __shfl_xor within the 32-lane group; lane 0 writes the scalar.

__global__ __launch_bounds__(256) void distmult_kernel(
    const float* __restrict__ src,
    const float* __restrict__ dst,
    const float* __restrict__ M,
    const int* __restrict__ rel_idx,
    float* __restrict__ out,
    int B)
{
    const int rel = rel_idx[0];
    const int lane = threadIdx.x & 31;              // lane within the row-group
    // rel row: 128 floats; each lane keeps its 4 coefficients in registers.
    const float4 r4 = reinterpret_cast<const float4*>(M + (size_t)rel * 128)[lane];

    const int group   = (int)((blockIdx.x * blockDim.x + threadIdx.x) >> 5);
    const int ngroups = (int)((gridDim.x * blockDim.x) >> 5);

    for (int row = group; row < B; row += ngroups) {
        const size_t base = (size_t)row * 128;
        const float4 s4 = reinterpret_cast<const float4*>(src + base)[lane];
        const float4 d4 = reinterpret_cast<const float4*>(dst + base)[lane];

        float acc = s4.x * r4.x * d4.x
                  + s4.y * r4.y * d4.y
                  + s4.z * r4.z * d4.z
                  + s4.w * r4.w * d4.w;

        // Reduce across the 32 lanes of this row-group. XOR masks 1..16 stay
        // within each 32-lane half of the wave64.
        #pragma unroll
        for (int m = 16; m > 0; m >>= 1)
            acc += __shfl_xor(acc, m);

        if (lane == 0) out[row] = acc;
    }
}

extern "C" void kernel_launch(void* const* d_in, const int* in_sizes, int n_in,
                              void* d_out, int out_size, void* d_ws, size_t ws_size,
                              hipStream_t stream)
{
    const float* src = (const float*)d_in[0];   // [B,128] f32
    const float* dst = (const float*)d_in[1];   // [B,128] f32
    const float* M   = (const float*)d_in[2];   // [1000,128] f32
    const int*   rel = (const int*)d_in[3];     // scalar (1-elem int array)
    float* out = (float*)d_out;                 // [B] f32 (shape [B,1,1])

    const int B = in_sizes[0] / 128;

    const int block = 256;
    const int grid  = 2048;   // 8 blocks/CU on 256 CUs; grid-stride covers B
    distmult_kernel<<<grid, block, 0, stream>>>(src, dst, M, rel, out, B);
}